// Round 4
// baseline (509.239 us; speedup 1.0000x reference)
//
#include <hip/hip_runtime.h>
#include <hip/hip_bf16.h>

#define N_NODES 100000
#define N_GRAPHS 512

// ---------------- degree count ----------------
__global__ void count_kernel(const int* __restrict__ dst, int* __restrict__ cnt, int E) {
    int i = blockIdx.x * blockDim.x + threadIdx.x;
    if (i < E) atomicAdd(&cnt[dst[i]], 1);
}

// dis[i] = 1/sqrt(deg_i + 1)   (self-loop included)
__global__ void dis_kernel(const int* __restrict__ cnt, float* __restrict__ dis, int n) {
    int i = blockIdx.x * blockDim.x + threadIdx.x;
    if (i < n) dis[i] = (float)(1.0 / sqrt((double)(cnt[i] + 1)));
}

// ---------------- exclusive scan (3 kernels, 1024 items/block) ----------------
__global__ void scan1_kernel(const int* __restrict__ cnt, int* __restrict__ offs,
                             int* __restrict__ bsums, int n) {
    const int t = threadIdx.x, lane = t & 63, w = t >> 6;
    const int base = blockIdx.x * 1024 + t * 4;
    int v0 = (base + 0 < n) ? cnt[base + 0] : 0;
    int v1 = (base + 1 < n) ? cnt[base + 1] : 0;
    int v2 = (base + 2 < n) ? cnt[base + 2] : 0;
    int v3 = (base + 3 < n) ? cnt[base + 3] : 0;
    int s = v0 + v1 + v2 + v3;
    int incl = s;
    #pragma unroll
    for (int off = 1; off < 64; off <<= 1) {
        int y = __shfl_up(incl, off);
        if (lane >= off) incl += y;
    }
    __shared__ int wsum[4];
    if (lane == 63) wsum[w] = incl;
    __syncthreads();
    int wbase = 0;
    #pragma unroll
    for (int k = 0; k < 4; ++k) if (k < w) wbase += wsum[k];
    int run = wbase + incl - s;   // exclusive prefix at this thread's first item
    if (base + 0 < n) offs[base + 0] = run; run += v0;
    if (base + 1 < n) offs[base + 1] = run; run += v1;
    if (base + 2 < n) offs[base + 2] = run; run += v2;
    if (base + 3 < n) offs[base + 3] = run;
    if (t == 255) bsums[blockIdx.x] = wbase + incl;  // block total
}

__global__ void scan2_kernel(int* __restrict__ bsums, int nb) {
    const int t = threadIdx.x, lane = t & 63, w = t >> 6;  // 128 threads
    int s = (t < nb) ? bsums[t] : 0;
    int incl = s;
    #pragma unroll
    for (int off = 1; off < 64; off <<= 1) {
        int y = __shfl_up(incl, off);
        if (lane >= off) incl += y;
    }
    __shared__ int wsum[2];
    if (lane == 63) wsum[w] = incl;
    __syncthreads();
    int wbase = (w == 1) ? wsum[0] : 0;
    if (t < nb) bsums[t] = wbase + incl - s;  // exclusive
}

__global__ void scan3_kernel(int* __restrict__ offs, const int* __restrict__ bsums,
                             int* __restrict__ cursor, int n) {
    int i = blockIdx.x * blockDim.x + threadIdx.x;
    if (i < n) {
        int v = offs[i] + bsums[i >> 10];
        offs[i] = v;
        cursor[i] = v;
    }
}

// ---------------- CSR fill ----------------
__global__ void fill_kernel(const int* __restrict__ src, const int* __restrict__ dst,
                            const float* __restrict__ dis, int* __restrict__ cursor,
                            int* __restrict__ csr_src, float* __restrict__ csr_norm, int E) {
    int i = blockIdx.x * blockDim.x + threadIdx.x;
    if (i < E) {
        int s = src[i], d = dst[i];
        int pos = atomicAdd(&cursor[d], 1);
        csr_src[pos] = s;
        csr_norm[pos] = dis[s] * dis[d];
    }
}

// ---------------- fused GCN layer: batched vectorized CSR gather + dense ----------
// VEC floats/lane; LPR lanes cover one row; EPW edge slots per wave per step;
// UNROLL steps batched -> 32 edges in flight per wave. sched_barrier(0) pins
// the load clusters so the scheduler cannot re-serialize them (R3 lesson:
// without the pin, VGPR stayed 36 and loads were sunk next to their FMAs).
template <int C_IN, int C_OUT>
__launch_bounds__(256, 4)
__global__ void gcn_layer(const float* __restrict__ h_in, const int* __restrict__ offs,
                          const int* __restrict__ cnt, const int* __restrict__ csr_src,
                          const float* __restrict__ csr_norm, const float* __restrict__ dis,
                          const float* __restrict__ W, const float* __restrict__ B,
                          float* __restrict__ h_out, int n) {
    constexpr int VEC = (C_IN >= 4) ? 4 : C_IN;        // 2 for layer1, else 4
    constexpr int LPR = C_IN / VEC;                     // lanes per row: 1,4,8,16
    constexpr int EPW = 64 / LPR;                       // edge slots: 64,16,8,4
    constexpr int LOGL = (LPR == 1) ? 0 : (LPR == 4) ? 2 : (LPR == 8) ? 3 : 4;
    constexpr int UNROLL = (EPW < 32) ? (32 / EPW) : 1; // 32 edges in flight
    constexpr bool LDSW = (C_IN * C_OUT * 4 <= 8192);   // stage small W in LDS

    __shared__ float sAgg[4][C_IN];
    __shared__ float sW[LDSW ? C_IN * C_OUT : 1];
    __shared__ float sB[LDSW ? C_OUT : 1];

    if (LDSW) {
        for (int i = threadIdx.x; i < C_IN * C_OUT; i += 256) sW[i] = W[i];
        if (threadIdx.x < C_OUT) sB[threadIdx.x] = B[threadIdx.x];
    }

    const int wave = threadIdx.x >> 6;
    const int lane = threadIdx.x & 63;
    const int node = (blockIdx.x << 2) + wave;
    const bool valid = node < n;

    const int cb = (lane & (LPR - 1)) * VEC;   // channel base for this lane
    const int sub = lane >> LOGL;              // edge slot within wave

    const int start = valid ? offs[node] : 0;
    const int m = valid ? cnt[node] : 0;

    float acc[VEC];
    #pragma unroll
    for (int v = 0; v < VEC; ++v) acc[v] = 0.f;

    for (int j = sub; j < m; j += UNROLL * EPW) {
        int ss[UNROLL];
        float nn[UNROLL];
        #pragma unroll
        for (int u = 0; u < UNROLL; ++u) {
            const int jj = j + u * EPW;
            const bool ok = jj < m;
            const int e = start + (ok ? jj : 0);   // dummy slots re-read edge 0 (cache-hot)
            ss[u] = csr_src[e];
            nn[u] = ok ? csr_norm[e] : 0.f;
        }
        __builtin_amdgcn_sched_barrier(0);   // all index/norm loads issued & in flight
        if constexpr (VEC == 4) {
            float4 hv[UNROLL];
            #pragma unroll
            for (int u = 0; u < UNROLL; ++u)
                hv[u] = *(const float4*)(h_in + (size_t)ss[u] * C_IN + cb);
            __builtin_amdgcn_sched_barrier(0);  // all gathers issued & in flight
            #pragma unroll
            for (int u = 0; u < UNROLL; ++u) {
                acc[0] = fmaf(nn[u], hv[u].x, acc[0]);
                acc[1] = fmaf(nn[u], hv[u].y, acc[1]);
                acc[2] = fmaf(nn[u], hv[u].z, acc[2]);
                acc[3] = fmaf(nn[u], hv[u].w, acc[3]);
            }
        } else {
            float2 hv[UNROLL];
            #pragma unroll
            for (int u = 0; u < UNROLL; ++u)
                hv[u] = *(const float2*)(h_in + (size_t)ss[u] * C_IN + cb);
            __builtin_amdgcn_sched_barrier(0);
            #pragma unroll
            for (int u = 0; u < UNROLL; ++u) {
                acc[0] = fmaf(nn[u], hv[u].x, acc[0]);
                acc[1] = fmaf(nn[u], hv[u].y, acc[1]);
            }
        }
    }
    // butterfly reduce across edge slots sharing the same channels
    #pragma unroll
    for (int off = 32; off >= LPR; off >>= 1) {
        #pragma unroll
        for (int v = 0; v < VEC; ++v) acc[v] += __shfl_xor(acc[v], off);
    }

    if (valid && lane < LPR) {
        const float d0 = dis[node];
        const float nm = d0 * d0;                 // self-loop, norm = dis^2
        const float* hp = h_in + (size_t)node * C_IN + cb;
        #pragma unroll
        for (int v = 0; v < VEC; ++v) acc[v] = fmaf(nm, hp[v], acc[v]);
        #pragma unroll
        for (int v = 0; v < VEC; ++v) sAgg[wave][cb + v] = acc[v];
    }
    __syncthreads();

    if (valid) {
        #pragma unroll
        for (int o = lane; o < C_OUT; o += 64) {
            float v = LDSW ? sB[o] : B[o];
            #pragma unroll
            for (int k = 0; k < C_IN; ++k) {
                const float w = LDSW ? sW[k * C_OUT + o] : W[k * C_OUT + o];
                v = fmaf(sAgg[wave][k], w, v);
            }
            h_out[(size_t)node * C_OUT + o] = fmaxf(v, 0.f);
        }
    }
}

// ---------------- segment-max pooling (batch sorted, values >= 0) ----------------
__global__ void pool_kernel(const float* __restrict__ h, const int* __restrict__ batch,
                            float* __restrict__ pooled, int n) {
    const int c = threadIdx.x;         // 128 channels
    const int n0 = blockIdx.x * 64;
    const int n1 = min(n0 + 64, n);
    int curg = batch[n0];
    float run = 0.f;
    for (int nn = n0; nn < n1; ++nn) {
        int g = batch[nn];
        if (g != curg) {
            atomicMax((int*)&pooled[curg * 128 + c], __float_as_int(run));
            curg = g;
            run = 0.f;
        }
        run = fmaxf(run, h[nn * 128 + c]);
    }
    atomicMax((int*)&pooled[curg * 128 + c], __float_as_int(run));
}

// ---------------- MLP head: relu(pooled @ W5 + b5) @ W6 + b6 ----------------
__global__ void mlp_kernel(const float* __restrict__ pooled,
                           const float* __restrict__ W5, const float* __restrict__ b5,
                           const float* __restrict__ W6, const float* __restrict__ b6,
                           float* __restrict__ out) {
    const int g = blockIdx.x;
    const int t = threadIdx.x;  // 64 threads
    __shared__ float row[128];
    __shared__ float hid[64];
    row[t] = pooled[g * 128 + t];
    row[64 + t] = pooled[g * 128 + 64 + t];
    __syncthreads();
    float v = b5[t];
    #pragma unroll 8
    for (int c = 0; c < 128; ++c) v = fmaf(row[c], W5[c * 64 + t], v);
    hid[t] = fmaxf(v, 0.f);
    __syncthreads();
    if (t < 10) {
        float o = b6[t];
        #pragma unroll 8
        for (int c = 0; c < 64; ++c) o = fmaf(hid[c], W6[c * 10 + t], o);
        out[g * 10 + t] = o;
    }
}

extern "C" void kernel_launch(void* const* d_in, const int* in_sizes, int n_in,
                              void* d_out, int out_size, void* d_ws, size_t ws_size,
                              hipStream_t stream) {
    const float* x     = (const float*)d_in[0];
    const int*   ei    = (const int*)d_in[1];
    const int*   batch = (const int*)d_in[2];
    const float* W1 = (const float*)d_in[3];  const float* b1 = (const float*)d_in[4];
    const float* W2 = (const float*)d_in[5];  const float* b2 = (const float*)d_in[6];
    const float* W3 = (const float*)d_in[7];  const float* b3 = (const float*)d_in[8];
    const float* W4 = (const float*)d_in[9];  const float* b4 = (const float*)d_in[10];
    const float* W5 = (const float*)d_in[11]; const float* b5 = (const float*)d_in[12];
    const float* W6 = (const float*)d_in[13]; const float* b6 = (const float*)d_in[14];
    float* out = (float*)d_out;

    const int N = in_sizes[0] / 2;       // 100000
    const int E = in_sizes[1] / 2;       // 1600000
    const int G = out_size / 10;         // 512
    const int* src = ei;
    const int* dst = ei + E;

    // workspace layout
    char* p = (char*)d_ws;
    auto take = [&](size_t bytes) -> void* {
        void* r = (void*)p;
        p += (bytes + 255) & ~(size_t)255;
        return r;
    };
    int*   cnt      = (int*)take((size_t)N * 4);
    int*   offs     = (int*)take((size_t)N * 4);
    int*   cursor   = (int*)take((size_t)N * 4);
    int*   bsums    = (int*)take(512 * 4);
    float* dis      = (float*)take((size_t)N * 4);
    int*   csr_src  = (int*)take((size_t)E * 4);
    float* csr_norm = (float*)take((size_t)E * 4);
    float* hA       = (float*)take((size_t)N * 64 * 4);    // h1(16), h3(64)
    float* hB       = (float*)take((size_t)N * 128 * 4);   // h2(32), h4(128)
    float* pooled   = (float*)take((size_t)G * 128 * 4);

    hipMemsetAsync(cnt, 0, (size_t)N * 4, stream);
    hipMemsetAsync(pooled, 0, (size_t)G * 128 * 4, stream);

    count_kernel<<<(E + 255) / 256, 256, 0, stream>>>(dst, cnt, E);
    dis_kernel<<<(N + 255) / 256, 256, 0, stream>>>(cnt, dis, N);

    const int NB = (N + 1023) / 1024;    // 98
    scan1_kernel<<<NB, 256, 0, stream>>>(cnt, offs, bsums, N);
    scan2_kernel<<<1, 128, 0, stream>>>(bsums, NB);
    scan3_kernel<<<(N + 255) / 256, 256, 0, stream>>>(offs, bsums, cursor, N);

    fill_kernel<<<(E + 255) / 256, 256, 0, stream>>>(src, dst, dis, cursor, csr_src, csr_norm, E);

    const int LBLK = (N + 3) / 4;  // 4 nodes per 256-thread block (one wave per node)
    gcn_layer<2, 16><<<LBLK, 256, 0, stream>>>(x,  offs, cnt, csr_src, csr_norm, dis, W1, b1, hA, N);
    gcn_layer<16, 32><<<LBLK, 256, 0, stream>>>(hA, offs, cnt, csr_src, csr_norm, dis, W2, b2, hB, N);
    gcn_layer<32, 64><<<LBLK, 256, 0, stream>>>(hB, offs, cnt, csr_src, csr_norm, dis, W3, b3, hA, N);
    gcn_layer<64, 128><<<LBLK, 256, 0, stream>>>(hA, offs, cnt, csr_src, csr_norm, dis, W4, b4, hB, N);

    pool_kernel<<<(N + 63) / 64, 128, 0, stream>>>(hB, batch, pooled, N);
    mlp_kernel<<<G, 64, 0, stream>>>(pooled, W5, b5, W6, b6, out);
}

// Round 5
// 465.817 us; speedup vs baseline: 1.0932x; 1.0932x over previous
//
#include <hip/hip_runtime.h>
#include <hip/hip_bf16.h>

#define N_NODES 100000
#define N_GRAPHS 512

typedef __attribute__((ext_vector_type(4))) float f32x4;
typedef __attribute__((ext_vector_type(2))) float f32x2;

// ---------------- degree count ----------------
__global__ void count_kernel(const int* __restrict__ dst, int* __restrict__ cnt, int E) {
    int i = blockIdx.x * blockDim.x + threadIdx.x;
    if (i < E) atomicAdd(&cnt[dst[i]], 1);
}

// dis[i] = 1/sqrt(deg_i + 1)   (self-loop included)
__global__ void dis_kernel(const int* __restrict__ cnt, float* __restrict__ dis, int n) {
    int i = blockIdx.x * blockDim.x + threadIdx.x;
    if (i < n) dis[i] = (float)(1.0 / sqrt((double)(cnt[i] + 1)));
}

// ---------------- exclusive scan (3 kernels, 1024 items/block) ----------------
__global__ void scan1_kernel(const int* __restrict__ cnt, int* __restrict__ offs,
                             int* __restrict__ bsums, int n) {
    const int t = threadIdx.x, lane = t & 63, w = t >> 6;
    const int base = blockIdx.x * 1024 + t * 4;
    int v0 = (base + 0 < n) ? cnt[base + 0] : 0;
    int v1 = (base + 1 < n) ? cnt[base + 1] : 0;
    int v2 = (base + 2 < n) ? cnt[base + 2] : 0;
    int v3 = (base + 3 < n) ? cnt[base + 3] : 0;
    int s = v0 + v1 + v2 + v3;
    int incl = s;
    #pragma unroll
    for (int off = 1; off < 64; off <<= 1) {
        int y = __shfl_up(incl, off);
        if (lane >= off) incl += y;
    }
    __shared__ int wsum[4];
    if (lane == 63) wsum[w] = incl;
    __syncthreads();
    int wbase = 0;
    #pragma unroll
    for (int k = 0; k < 4; ++k) if (k < w) wbase += wsum[k];
    int run = wbase + incl - s;   // exclusive prefix at this thread's first item
    if (base + 0 < n) offs[base + 0] = run; run += v0;
    if (base + 1 < n) offs[base + 1] = run; run += v1;
    if (base + 2 < n) offs[base + 2] = run; run += v2;
    if (base + 3 < n) offs[base + 3] = run;
    if (t == 255) bsums[blockIdx.x] = wbase + incl;  // block total
}

__global__ void scan2_kernel(int* __restrict__ bsums, int nb) {
    const int t = threadIdx.x, lane = t & 63, w = t >> 6;  // 128 threads
    int s = (t < nb) ? bsums[t] : 0;
    int incl = s;
    #pragma unroll
    for (int off = 1; off < 64; off <<= 1) {
        int y = __shfl_up(incl, off);
        if (lane >= off) incl += y;
    }
    __shared__ int wsum[2];
    if (lane == 63) wsum[w] = incl;
    __syncthreads();
    int wbase = (w == 1) ? wsum[0] : 0;
    if (t < nb) bsums[t] = wbase + incl - s;  // exclusive
}

__global__ void scan3_kernel(int* __restrict__ offs, const int* __restrict__ bsums,
                             int* __restrict__ cursor, int n) {
    int i = blockIdx.x * blockDim.x + threadIdx.x;
    if (i < n) {
        int v = offs[i] + bsums[i >> 10];
        offs[i] = v;
        cursor[i] = v;
    }
}

// ---------------- CSR fill ----------------
__global__ void fill_kernel(const int* __restrict__ src, const int* __restrict__ dst,
                            const float* __restrict__ dis, int* __restrict__ cursor,
                            int* __restrict__ csr_src, float* __restrict__ csr_norm, int E) {
    int i = blockIdx.x * blockDim.x + threadIdx.x;
    if (i < E) {
        int s = src[i], d = dst[i];
        int pos = atomicAdd(&cursor[d], 1);
        csr_src[pos] = s;
        csr_norm[pos] = dis[s] * dis[d];
    }
}

// ---------------- fused GCN layer ------------------------------------------------
// Inline-asm gather cluster: UNROLL global_load_dwordx4 issued back-to-back
// (asm volatile preserves mutual order; the compiler provably re-serialized
// plain-C batches — VGPR stayed 36 in R2-R4), then s_waitcnt vmcnt(0) +
// sched_barrier(0) (rule #18) before the FMA consumers.
template <int C_IN, int C_OUT>
__launch_bounds__(256, 4)
__global__ void gcn_layer(const float* __restrict__ h_in, const int* __restrict__ offs,
                          const int* __restrict__ cnt, const int* __restrict__ csr_src,
                          const float* __restrict__ csr_norm, const float* __restrict__ dis,
                          const float* __restrict__ W, const float* __restrict__ B,
                          float* __restrict__ h_out, int n) {
    constexpr int VEC = (C_IN >= 4) ? 4 : C_IN;        // 2 for layer1, else 4
    constexpr int LPR = C_IN / VEC;                     // lanes per row: 1,4,8,16
    constexpr int EPW = 64 / LPR;                       // edge slots: 64,16,8,4
    constexpr int LOGL = (LPR == 1) ? 0 : (LPR == 4) ? 2 : (LPR == 8) ? 3 : 4;
    constexpr int UNROLL = (EPW < 32) ? (32 / EPW) : 1; // 32 edge-slots per batch
    constexpr bool LDSW = (C_IN * C_OUT * 4 <= 8192);   // stage small W in LDS

    __shared__ float sAgg[4][C_IN];
    __shared__ float sW[LDSW ? C_IN * C_OUT : 1];
    __shared__ float sB[LDSW ? C_OUT : 1];

    if (LDSW) {
        for (int i = threadIdx.x; i < C_IN * C_OUT; i += 256) sW[i] = W[i];
        if (threadIdx.x < C_OUT) sB[threadIdx.x] = B[threadIdx.x];
    }

    const int wave = threadIdx.x >> 6;
    const int lane = threadIdx.x & 63;
    const int node = (blockIdx.x << 2) + wave;
    const bool valid = node < n;

    const int cb = (lane & (LPR - 1)) * VEC;   // channel base for this lane
    const int sub = lane >> LOGL;              // edge slot within wave

    const int start = valid ? offs[node] : 0;
    const int m = valid ? cnt[node] : 0;

    float acc[VEC];
    #pragma unroll
    for (int v = 0; v < VEC; ++v) acc[v] = 0.f;

    for (int j = sub; j < m; j += UNROLL * EPW) {
        int ss[UNROLL];
        float nn[UNROLL];
        #pragma unroll
        for (int u = 0; u < UNROLL; ++u) {
            const int jj = j + u * EPW;
            const bool ok = jj < m;
            const int e = start + (ok ? jj : 0);   // dummy slots re-read edge 0 (cache-hot)
            ss[u] = csr_src[e];
            nn[u] = ok ? csr_norm[e] : 0.f;
        }
        if constexpr (VEC == 4) {
            f32x4 hv[UNROLL];
            const float* ap[UNROLL];
            #pragma unroll
            for (int u = 0; u < UNROLL; ++u)
                ap[u] = h_in + (size_t)ss[u] * C_IN + cb;
            #pragma unroll
            for (int u = 0; u < UNROLL; ++u)
                asm volatile("global_load_dwordx4 %0, %1, off"
                             : "=v"(hv[u]) : "v"(ap[u]) : "memory");
            asm volatile("s_waitcnt vmcnt(0)" ::: "memory");
            __builtin_amdgcn_sched_barrier(0);   // rule #18: pin consumers below the wait
            #pragma unroll
            for (int u = 0; u < UNROLL; ++u) {
                acc[0] = fmaf(nn[u], hv[u].x, acc[0]);
                acc[1] = fmaf(nn[u], hv[u].y, acc[1]);
                acc[2] = fmaf(nn[u], hv[u].z, acc[2]);
                acc[3] = fmaf(nn[u], hv[u].w, acc[3]);
            }
        } else {
            f32x2 hv[UNROLL];
            #pragma unroll
            for (int u = 0; u < UNROLL; ++u)
                hv[u] = *(const f32x2*)(h_in + (size_t)ss[u] * C_IN + cb);
            #pragma unroll
            for (int u = 0; u < UNROLL; ++u) {
                acc[0] = fmaf(nn[u], hv[u].x, acc[0]);
                acc[1] = fmaf(nn[u], hv[u].y, acc[1]);
            }
        }
    }
    // butterfly reduce across edge slots sharing the same channels
    #pragma unroll
    for (int off = 32; off >= LPR; off >>= 1) {
        #pragma unroll
        for (int v = 0; v < VEC; ++v) acc[v] += __shfl_xor(acc[v], off);
    }

    if (valid && lane < LPR) {
        const float d0 = dis[node];
        const float nm = d0 * d0;                 // self-loop, norm = dis^2
        const float* hp = h_in + (size_t)node * C_IN + cb;
        #pragma unroll
        for (int v = 0; v < VEC; ++v) acc[v] = fmaf(nm, hp[v], acc[v]);
        #pragma unroll
        for (int v = 0; v < VEC; ++v) sAgg[wave][cb + v] = acc[v];
    }
    __syncthreads();

    if (valid) {
        #pragma unroll
        for (int o = lane; o < C_OUT; o += 64) {
            float v = LDSW ? sB[o] : B[o];
            #pragma unroll
            for (int k = 0; k < C_IN; ++k) {
                const float w = LDSW ? sW[k * C_OUT + o] : W[k * C_OUT + o];
                v = fmaf(sAgg[wave][k], w, v);
            }
            h_out[(size_t)node * C_OUT + o] = fmaxf(v, 0.f);
        }
    }
}

// ---------------- segment-max pooling (batch sorted, values >= 0) ----------------
__global__ void pool_kernel(const float* __restrict__ h, const int* __restrict__ batch,
                            float* __restrict__ pooled, int n) {
    const int c = threadIdx.x;         // 128 channels
    const int n0 = blockIdx.x * 64;
    const int n1 = min(n0 + 64, n);
    int curg = batch[n0];
    float run = 0.f;
    for (int nn = n0; nn < n1; ++nn) {
        int g = batch[nn];
        if (g != curg) {
            atomicMax((int*)&pooled[curg * 128 + c], __float_as_int(run));
            curg = g;
            run = 0.f;
        }
        run = fmaxf(run, h[nn * 128 + c]);
    }
    atomicMax((int*)&pooled[curg * 128 + c], __float_as_int(run));
}

// ---------------- MLP head: relu(pooled @ W5 + b5) @ W6 + b6 ----------------
__global__ void mlp_kernel(const float* __restrict__ pooled,
                           const float* __restrict__ W5, const float* __restrict__ b5,
                           const float* __restrict__ W6, const float* __restrict__ b6,
                           float* __restrict__ out) {
    const int g = blockIdx.x;
    const int t = threadIdx.x;  // 64 threads
    __shared__ float row[128];
    __shared__ float hid[64];
    row[t] = pooled[g * 128 + t];
    row[64 + t] = pooled[g * 128 + 64 + t];
    __syncthreads();
    float v = b5[t];
    #pragma unroll 8
    for (int c = 0; c < 128; ++c) v = fmaf(row[c], W5[c * 64 + t], v);
    hid[t] = fmaxf(v, 0.f);
    __syncthreads();
    if (t < 10) {
        float o = b6[t];
        #pragma unroll 8
        for (int c = 0; c < 64; ++c) o = fmaf(hid[c], W6[c * 10 + t], o);
        out[g * 10 + t] = o;
    }
}

extern "C" void kernel_launch(void* const* d_in, const int* in_sizes, int n_in,
                              void* d_out, int out_size, void* d_ws, size_t ws_size,
                              hipStream_t stream) {
    const float* x     = (const float*)d_in[0];
    const int*   ei    = (const int*)d_in[1];
    const int*   batch = (const int*)d_in[2];
    const float* W1 = (const float*)d_in[3];  const float* b1 = (const float*)d_in[4];
    const float* W2 = (const float*)d_in[5];  const float* b2 = (const float*)d_in[6];
    const float* W3 = (const float*)d_in[7];  const float* b3 = (const float*)d_in[8];
    const float* W4 = (const float*)d_in[9];  const float* b4 = (const float*)d_in[10];
    const float* W5 = (const float*)d_in[11]; const float* b5 = (const float*)d_in[12];
    const float* W6 = (const float*)d_in[13]; const float* b6 = (const float*)d_in[14];
    float* out = (float*)d_out;

    const int N = in_sizes[0] / 2;       // 100000
    const int E = in_sizes[1] / 2;       // 1600000
    const int G = out_size / 10;         // 512
    const int* src = ei;
    const int* dst = ei + E;

    // workspace layout
    char* p = (char*)d_ws;
    auto take = [&](size_t bytes) -> void* {
        void* r = (void*)p;
        p += (bytes + 255) & ~(size_t)255;
        return r;
    };
    int*   cnt      = (int*)take((size_t)N * 4);
    int*   offs     = (int*)take((size_t)N * 4);
    int*   cursor   = (int*)take((size_t)N * 4);
    int*   bsums    = (int*)take(512 * 4);
    float* dis      = (float*)take((size_t)N * 4);
    int*   csr_src  = (int*)take((size_t)E * 4);
    float* csr_norm = (float*)take((size_t)E * 4);
    float* hA       = (float*)take((size_t)N * 64 * 4);    // h1(16), h3(64)
    float* hB       = (float*)take((size_t)N * 128 * 4);   // h2(32), h4(128)
    float* pooled   = (float*)take((size_t)G * 128 * 4);

    hipMemsetAsync(cnt, 0, (size_t)N * 4, stream);
    hipMemsetAsync(pooled, 0, (size_t)G * 128 * 4, stream);

    count_kernel<<<(E + 255) / 256, 256, 0, stream>>>(dst, cnt, E);
    dis_kernel<<<(N + 255) / 256, 256, 0, stream>>>(cnt, dis, N);

    const int NB = (N + 1023) / 1024;    // 98
    scan1_kernel<<<NB, 256, 0, stream>>>(cnt, offs, bsums, N);
    scan2_kernel<<<1, 128, 0, stream>>>(bsums, NB);
    scan3_kernel<<<(N + 255) / 256, 256, 0, stream>>>(offs, bsums, cursor, N);

    fill_kernel<<<(E + 255) / 256, 256, 0, stream>>>(src, dst, dis, cursor, csr_src, csr_norm, E);

    const int LBLK = (N + 3) / 4;  // 4 nodes per 256-thread block (one wave per node)
    gcn_layer<2, 16><<<LBLK, 256, 0, stream>>>(x,  offs, cnt, csr_src, csr_norm, dis, W1, b1, hA, N);
    gcn_layer<16, 32><<<LBLK, 256, 0, stream>>>(hA, offs, cnt, csr_src, csr_norm, dis, W2, b2, hB, N);
    gcn_layer<32, 64><<<LBLK, 256, 0, stream>>>(hB, offs, cnt, csr_src, csr_norm, dis, W3, b3, hA, N);
    gcn_layer<64, 128><<<LBLK, 256, 0, stream>>>(hA, offs, cnt, csr_src, csr_norm, dis, W4, b4, hB, N);

    pool_kernel<<<(N + 63) / 64, 128, 0, stream>>>(hB, batch, pooled, N);
    mlp_kernel<<<G, 64, 0, stream>>>(pooled, W5, b5, W6, b6, out);
}